// Round 4
// baseline (44.928 us; speedup 1.0000x reference)
//
#include <hip/hip_runtime.h>

#define NB    384          // batch
#define ND    256          // embedding dim
#define HB    0x80808080u  // byte-MSB mask
#define KMUL  0x00204081u  // gathers bits {7,15,23,31} -> {28..31}
#define EPSF  1e-6f

#define NPART 768
#define WLUT_OFF 0
#define PART_OFF 16
#define ET_OFF   1024                  // ET[256][384] floats (e - eps)
#define JD_OFF   (ET_OFF + ND * NB)    // float4 jd[384][384]; 99328*4B, 16B aligned

// ---------------------------------------------------------------------------
// Kernel 1: transpose E -> ET[d][j] = e[j][d] - eps  (so e_i - ET = e_i-e_j+eps)
// 32x32 LDS tiles, coalesced both sides. Block 0 also builds the 16-entry wlut
// from the analytic per-task counts.
// ---------------------------------------------------------------------------
__global__ __launch_bounds__(256) void prep_kernel(
    const float* __restrict__ emb,
    const float* __restrict__ tw,
    const int*   __restrict__ rank,
    float* __restrict__ ws)
{
    __shared__ float    t[32][33];
    __shared__ unsigned hist[20];
    __shared__ double   wp[4];

    const int tid = threadIdx.x;
    const int dt  = blockIdx.x & 7;    // 8 d-tiles
    const int jt  = blockIdx.x >> 3;   // 12 j-tiles
    const int c   = tid & 31;
    const int r8  = tid >> 5;          // 0..7

    #pragma unroll
    for (int p = 0; p < 4; ++p) {
        const int j = jt * 32 + r8 + p * 8;
        const int d = dt * 32 + c;
        t[r8 + p * 8][c] = emb[(size_t)j * ND + d];   // coalesced read
    }
    __syncthreads();
    float* ET = ws + ET_OFF;
    #pragma unroll
    for (int p = 0; p < 4; ++p) {
        const int d = dt * 32 + r8 + p * 8;
        const int j = jt * 32 + c;
        ET[(size_t)d * NB + j] = t[c][r8 + p * 8] - EPSF;  // coalesced write
    }

    if (blockIdx.x == 0) {
        if (tid < 20) hist[tid] = 0u;
        __syncthreads();
        for (int e = tid; e < NB * 4; e += 256)
            atomicAdd(&hist[(e & 3) * 5 + rank[e]], 1u);
        __syncthreads();
        if (tid < 4) {
            double cnt = 0.0;
            unsigned below = 0;
            #pragma unroll
            for (int v = 0; v < 5; ++v) {
                unsigned hv = hist[tid * 5 + v];
                unsigned above = (unsigned)NB - below - hv;
                cnt += (double)hv * (double)below * (double)above;
                below += hv;
            }
            wp[tid] = (cnt > 0.0) ? (double)tw[tid] / cnt : 0.0;
        }
        __syncthreads();
        if (tid < 16) {
            double w = 0.0;
            if (tid & 1) w += wp[0];
            if (tid & 2) w += wp[1];
            if (tid & 4) w += wp[2];
            if (tid & 8) w += wp[3];
            ws[WLUT_OFF + tid] = (float)w;   // wlut[0]==0 absorbs masked triples
        }
    }
}

// ---------------------------------------------------------------------------
// Kernel 2: distances + packed per-(i,j) helpers. Block = 2 i-rows x all 384 j.
// ET reads are lane-coalesced; e_i rows are wave-uniform -> scalar (SMEM) loads.
// No LDS in the hot loop.
// ---------------------------------------------------------------------------
__global__ __launch_bounds__(384) void distpack_kernel(
    const float* __restrict__ emb,
    const int*   __restrict__ rank,
    const float* __restrict__ et,
    float4* __restrict__ jd)
{
    const int j  = threadIdx.x;          // 0..383
    const int i0 = blockIdx.x * 2;

    const float* e0 = emb + (size_t)i0 * ND;
    const float* e1 = e0 + ND;

    float a0 = 0.f, a1 = 0.f;
    #pragma unroll 8
    for (int d = 0; d < ND; ++d) {
        const float ev = et[(size_t)d * NB + j];  // coalesced vector load
        const float t0 = e0[d] - ev;              // s_load operand (uniform)
        const float t1 = e1[d] - ev;
        a0 = fmaf(t0, t0, a0);
        a1 = fmaf(t1, t1, a1);
    }

    const int4 rj4 = *reinterpret_cast<const int4*>(rank + j * 4);
    const unsigned rpj = (unsigned)rj4.x | ((unsigned)rj4.y << 8) |
                         ((unsigned)rj4.z << 16) | ((unsigned)rj4.w << 24);
    const unsigned hj = HB - rpj;

    const int4* rr = reinterpret_cast<const int4*>(rank);
    const int4 ri0 = rr[i0], ri1 = rr[i0 + 1];    // uniform -> scalar
    const unsigned rpi0 = (unsigned)ri0.x | ((unsigned)ri0.y << 8) |
                          ((unsigned)ri0.z << 16) | ((unsigned)ri0.w << 24);
    const unsigned rpi1 = (unsigned)ri1.x | ((unsigned)ri1.y << 8) |
                          ((unsigned)ri1.z << 16) | ((unsigned)ri1.w << 24);

    float4 v0, v1;
    v0.x = sqrtf(a0) + 1.0f;                          // d_ij + MARGIN
    v0.y = __uint_as_float(hj);
    v0.z = __uint_as_float(~(rpj + (HB - rpi0)) & HB); // gt[i0,j] bits
    v0.w = 0.f;
    v1.x = sqrtf(a1) + 1.0f;
    v1.y = __uint_as_float(hj);
    v1.z = __uint_as_float(~(rpj + (HB - rpi1)) & HB); // gt[i0+1,j] bits
    v1.w = 0.f;
    jd[(size_t)i0 * NB + j]       = v0;
    jd[(size_t)(i0 + 1) * NB + j] = v1;
}

// ---------------------------------------------------------------------------
// Kernel 3: partial[b] = sum relu(d_ij - d_ik + 1) * wlut[bits_ij & bits_jk]
// Block = (i, 192-wide j-slice); thread owns k = tid and tid+192.
// jd[j] is wave-uniform -> s_load_dwordx4 (scalar cache, off the LDS pipe).
// Only LDS traffic in the loop: 2 conflict-free wlut b32 gathers per j.
// ---------------------------------------------------------------------------
__global__ __launch_bounds__(192) void mtrl_kernel(
    const int*    __restrict__ rank,
    const float*  __restrict__ wlut,
    const float4* __restrict__ jd,
    float* __restrict__ partial)
{
    __shared__ float wl[16];
    __shared__ float red[3];

    const int tid = threadIdx.x;
    const int bi  = blockIdx.x >> 1;
    const int j0  = (blockIdx.x & 1) * 192;
    const float4* jrow = jd + (size_t)bi * NB;

    if (tid < 16) wl[tid] = wlut[tid];

    const int ka = tid, kb = tid + 192;
    const float dika = jrow[ka].x - 1.0f;   // raw d_ik (per-lane vector load)
    const float dikb = jrow[kb].x - 1.0f;
    const int4 ra4 = *reinterpret_cast<const int4*>(rank + ka * 4);
    const int4 rb4 = *reinterpret_cast<const int4*>(rank + kb * 4);
    const unsigned rpka = (unsigned)ra4.x | ((unsigned)ra4.y << 8) |
                          ((unsigned)ra4.z << 16) | ((unsigned)ra4.w << 24);
    const unsigned rpkb = (unsigned)rb4.x | ((unsigned)rb4.y << 8) |
                          ((unsigned)rb4.z << 16) | ((unsigned)rb4.w << 24);
    __syncthreads();

    float sa = 0.f, sb = 0.f;
    #pragma unroll 8
    for (int jj = 0; jj < 192; ++jj) {
        const float4 d4 = jrow[j0 + jj];                // uniform -> s_load_dwordx4
        const unsigned hj  = __float_as_uint(d4.y);
        const unsigned mij = __float_as_uint(d4.z);
        const unsigned ba  = ((rpka + hj) ^ HB) & mij;  // gt[i,j] & gt[j,ka]
        const unsigned bb  = ((rpkb + hj) ^ HB) & mij;
        const float wa = wl[(ba * KMUL) >> 28];
        const float wb = wl[(bb * KMUL) >> 28];
        const float va = fmaxf(d4.x - dika, 0.f);       // relu(d_ij - d_ik + 1)
        const float vb = fmaxf(d4.x - dikb, 0.f);
        sa = fmaf(va, wa, sa);
        sb = fmaf(vb, wb, sb);
    }

    float t = sa + sb;
    #pragma unroll
    for (int off = 32; off > 0; off >>= 1)
        t += __shfl_down(t, off);
    if ((tid & 63) == 0) red[tid >> 6] = t;
    __syncthreads();
    if (tid == 0)
        partial[blockIdx.x] = red[0] + red[1] + red[2];
}

// ---------------------------------------------------------------------------
// Kernel 4: reduce 768 partials -> out[0]
// ---------------------------------------------------------------------------
__global__ __launch_bounds__(256) void reduce_kernel(
    const float* __restrict__ partial, float* __restrict__ out)
{
    __shared__ float r[4];
    const int tid = threadIdx.x;
    float t = 0.f;
    #pragma unroll
    for (int p = tid; p < NPART; p += 256) t += partial[p];
    #pragma unroll
    for (int off = 32; off > 0; off >>= 1)
        t += __shfl_down(t, off);
    if ((tid & 63) == 0) r[tid >> 6] = t;
    __syncthreads();
    if (tid == 0) out[0] = r[0] + r[1] + r[2] + r[3];
}

extern "C" void kernel_launch(void* const* d_in, const int* in_sizes, int n_in,
                              void* d_out, int out_size, void* d_ws, size_t ws_size,
                              hipStream_t stream)
{
    (void)in_sizes; (void)n_in; (void)out_size; (void)ws_size;
    const float* emb  = (const float*)d_in[0];
    const float* tw   = (const float*)d_in[1];
    const int*   rank = (const int*)d_in[2];
    float* ws  = (float*)d_ws;
    float* out = (float*)d_out;

    prep_kernel<<<96, 256, 0, stream>>>(emb, tw, rank, ws);
    distpack_kernel<<<NB / 2, NB, 0, stream>>>(
        emb, rank, ws + ET_OFF, reinterpret_cast<float4*>(ws + JD_OFF));
    mtrl_kernel<<<NB * 2, 192, 0, stream>>>(
        rank, ws + WLUT_OFF, reinterpret_cast<const float4*>(ws + JD_OFF),
        ws + PART_OFF);
    reduce_kernel<<<1, 256, 0, stream>>>(ws + PART_OFF, out);
}

// Round 5
// 34.017 us; speedup vs baseline: 1.3207x; 1.3207x over previous
//
#include <hip/hip_runtime.h>

#define NB   384
#define ND   256
#define EPSF 1e-6f

// ws layout (floats):
#define WF_OFF   0                      // wf[4] = tw_t / count_t
#define PART_OFF 16                     // partial[384]
#define RP_OFF   512                    // rp[384] (u32 packed ranks)
#define ET_OFF   1024                   // ET[256][384] = emb^T - eps
#define D_OFF    (ET_OFF + ND * NB)     // D[384][384]

// ---------------------------------------------------------------------------
// K1: transpose emb -> ET[d][j] = e[j][d] - eps; block 0: per-task weights
// wf[t] = tw_t / count_t (analytic count from rank histogram); block 1: pack
// ranks rp[j] = r0|r1<<8|r2<<16|r3<<24.
// ---------------------------------------------------------------------------
__global__ __launch_bounds__(256) void prep_kernel(
    const float* __restrict__ emb,
    const float* __restrict__ tw,
    const int*   __restrict__ rank,
    float* __restrict__ ws)
{
    __shared__ float    t[32][33];
    __shared__ unsigned hist[20];

    const int tid = threadIdx.x;
    const int dt  = blockIdx.x & 7;
    const int jt  = blockIdx.x >> 3;
    const int c   = tid & 31;
    const int r8  = tid >> 5;

    #pragma unroll
    for (int p = 0; p < 4; ++p) {
        const int j = jt * 32 + r8 + p * 8;
        const int d = dt * 32 + c;
        t[r8 + p * 8][c] = emb[(size_t)j * ND + d];
    }
    __syncthreads();
    float* ET = ws + ET_OFF;
    #pragma unroll
    for (int p = 0; p < 4; ++p) {
        const int d = dt * 32 + r8 + p * 8;
        const int j = jt * 32 + c;
        ET[(size_t)d * NB + j] = t[c][r8 + p * 8] - EPSF;
    }

    if (blockIdx.x == 0) {
        if (tid < 20) hist[tid] = 0u;
        __syncthreads();
        for (int e = tid; e < NB * 4; e += 256)
            atomicAdd(&hist[(e & 3) * 5 + rank[e]], 1u);
        __syncthreads();
        if (tid < 4) {
            double cnt = 0.0;
            unsigned below = 0;
            #pragma unroll
            for (int v = 0; v < 5; ++v) {
                unsigned hv = hist[tid * 5 + v];
                unsigned above = (unsigned)NB - below - hv;
                cnt += (double)hv * (double)below * (double)above;
                below += hv;
            }
            ws[WF_OFF + tid] = (cnt > 0.0) ? (float)((double)tw[tid] / cnt) : 0.f;
        }
    }
    if (blockIdx.x == 1) {
        unsigned* rp = reinterpret_cast<unsigned*>(ws + RP_OFF);
        for (int j = tid; j < NB; j += 256) {
            const int4 r4 = *reinterpret_cast<const int4*>(rank + j * 4);
            rp[j] = (unsigned)r4.x | ((unsigned)r4.y << 8) |
                    ((unsigned)r4.z << 16) | ((unsigned)r4.w << 24);
        }
    }
}

// ---------------------------------------------------------------------------
// K2: D[i][j] = sqrt(sum_d (e_i[d] - (e_j[d]-eps))^2). 2 i-rows per block;
// ET reads lane-coalesced, e_i rows wave-uniform (scalar path).
// ---------------------------------------------------------------------------
__global__ __launch_bounds__(384) void dist_kernel(
    const float* __restrict__ emb,
    const float* __restrict__ et,
    float* __restrict__ D)
{
    const int j  = threadIdx.x;
    const int i0 = blockIdx.x * 2;
    const float* e0 = emb + (size_t)i0 * ND;
    const float* e1 = e0 + ND;

    float a0 = 0.f, a1 = 0.f;
    #pragma unroll 8
    for (int d = 0; d < ND; ++d) {
        const float ev = et[(size_t)d * NB + j];
        const float t0 = e0[d] - ev;
        const float t1 = e1[d] - ev;
        a0 = fmaf(t0, t0, a0);
        a1 = fmaf(t1, t1, a1);
    }
    D[(size_t)i0 * NB + j]       = sqrtf(a0);
    D[(size_t)(i0 + 1) * NB + j] = sqrtf(a1);
}

// ---------------------------------------------------------------------------
// K3: one block per row i. Bitonic-sort (d, rankpack) ascending by d (512 slots,
// +INF pads). Then per sorted position p (= both a j-role and a k-role):
//   j-role:  + thr_p * sum_t wf_t * #{q<P: r^t_q < r^t_p}      [r^t_p < r^t_i]
//   k-role:  - d_p  * sum_t wf_t * #{q>=Q: r^t_k < r^t_q < r^t_i}
// with P = #{q: d_q < thr_p}, Q = #{q: d_q+1 <= d_p}  (identical float
// predicate on both sides -> pair sets match exactly).
// Counts come from per-wave cumulative-rank ballot masks + wave prefix table.
// ---------------------------------------------------------------------------
__global__ __launch_bounds__(512) void loss_kernel(
    const float*    __restrict__ D,
    const unsigned* __restrict__ rp,
    const float*    __restrict__ wf,
    float* __restrict__ partial)
{
    __shared__ unsigned long long sh64[512];
    __shared__ float ks[512];
    __shared__ unsigned long long cm[8][16];   // [wave][t*4+w]: mask of r^t <= w
    __shared__ unsigned cumtab[9][16];         // exclusive wave-prefix popcounts
    __shared__ float red[8];

    const int p  = threadIdx.x;
    const int bi = blockIdx.x;

    unsigned long long kv;
    if (p < NB) {
        const unsigned kb = __float_as_uint(D[(size_t)bi * NB + p]); // d>0: bit order == value order
        kv = ((unsigned long long)kb << 32) | rp[p];
    } else {
        kv = 0x7F800000FFFFFFFFull;            // +INF key, rank bytes 0xFF (excluded)
    }

    // bitonic sort, value-in-register
    for (int size = 2; size <= 512; size <<= 1) {
        for (int stride = size >> 1; stride > 0; stride >>= 1) {
            sh64[p] = kv;
            __syncthreads();
            const unsigned long long other = sh64[p ^ stride];
            __syncthreads();
            const bool keepMin = ((p & stride) == 0) == ((p & size) == 0);
            const bool less = kv < other;
            kv = (less == keepMin) ? kv : other;
        }
    }

    const unsigned rsv = (unsigned)kv;                       // own sorted rank pack
    ks[p] = __uint_as_float((unsigned)(kv >> 32));           // own sorted distance
    const int wv = p >> 6;
    #pragma unroll
    for (int t = 0; t < 4; ++t) {
        const unsigned rt = (rsv >> (8 * t)) & 0xFFu;
        #pragma unroll
        for (int w = 0; w < 4; ++w) {
            const unsigned long long m = __ballot(rt <= (unsigned)w);
            if ((p & 63) == 0) cm[wv][t * 4 + w] = m;
        }
    }
    __syncthreads();
    if (p < 16) {
        unsigned c = 0;
        #pragma unroll
        for (int w2 = 0; w2 < 8; ++w2) {
            cumtab[w2][p] = c;
            c += (unsigned)__popcll(cm[w2][p]);
        }
        cumtab[8][p] = c;                                    // totals (pads excluded by rank filter)
    }
    __syncthreads();

    float contrib = 0.f;
    if (p < NB) {
        const float key = ks[p];
        const float thr = key + 1.0f;

        int P = 0;                                           // #{q: ks[q] < thr}
        #pragma unroll
        for (int s = 256; s > 0; s >>= 1) {
            const int cand = P + s;
            if (ks[cand - 1] < thr) P = cand;
        }
        int Q = 0;                                           // #{q: ks[q]+1 <= key}
        #pragma unroll
        for (int s = 256; s > 0; s >>= 1) {
            const int cand = Q + s;
            if (ks[cand - 1] + 1.0f <= key) Q = cand;
        }

        const int Pwv = P >> 6, Qwv = Q >> 6;
        const unsigned long long Pmask = (1ull << (P & 63)) - 1ull;
        const unsigned long long Qmask = (1ull << (Q & 63)) - 1ull;
        const unsigned rip = rp[bi];                         // row-i ranks (uniform)

        float jacc = 0.f, kacc = 0.f;
        #pragma unroll
        for (int t = 0; t < 4; ++t) {
            const int ri = (int)((rip >> (8 * t)) & 0xFFu);
            const int ro = (int)((rsv >> (8 * t)) & 0xFFu);  // own rank (j-role and k-role)
            const float wt = wf[t];
            if (ro > 0 && ro < ri) {                         // j-role
                const int w = t * 4 + (ro - 1);
                const unsigned N = cumtab[Pwv][w] +
                                   (unsigned)__popcll(cm[Pwv][w] & Pmask);
                jacc += wt * (float)N;
            }
            if (ro + 1 < ri) {                               // k-role: ranks in (ro, ri)
                const int wh = t * 4 + (ri - 1);
                const int wl = t * 4 + ro;
                const unsigned cQh = cumtab[Qwv][wh] +
                                     (unsigned)__popcll(cm[Qwv][wh] & Qmask);
                const unsigned cQl = cumtab[Qwv][wl] +
                                     (unsigned)__popcll(cm[Qwv][wl] & Qmask);
                const unsigned C = (cumtab[8][wh] - cQh) - (cumtab[8][wl] - cQl);
                kacc += wt * (float)C;
            }
        }
        contrib = jacc * thr - kacc * key;
    }

    #pragma unroll
    for (int off = 32; off > 0; off >>= 1)
        contrib += __shfl_down(contrib, off);
    if ((p & 63) == 0) red[p >> 6] = contrib;
    __syncthreads();
    if (p == 0) {
        float s = 0.f;
        #pragma unroll
        for (int q = 0; q < 8; ++q) s += red[q];
        partial[bi] = s;
    }
}

// ---------------------------------------------------------------------------
// K4: reduce 384 partials -> out[0]
// ---------------------------------------------------------------------------
__global__ __launch_bounds__(256) void reduce_kernel(
    const float* __restrict__ partial, float* __restrict__ out)
{
    __shared__ float r[4];
    const int tid = threadIdx.x;
    float t = 0.f;
    for (int p = tid; p < NB; p += 256) t += partial[p];
    #pragma unroll
    for (int off = 32; off > 0; off >>= 1)
        t += __shfl_down(t, off);
    if ((tid & 63) == 0) r[tid >> 6] = t;
    __syncthreads();
    if (tid == 0) out[0] = r[0] + r[1] + r[2] + r[3];
}

extern "C" void kernel_launch(void* const* d_in, const int* in_sizes, int n_in,
                              void* d_out, int out_size, void* d_ws, size_t ws_size,
                              hipStream_t stream)
{
    (void)in_sizes; (void)n_in; (void)out_size; (void)ws_size;
    const float* emb  = (const float*)d_in[0];
    const float* tw   = (const float*)d_in[1];
    const int*   rank = (const int*)d_in[2];
    float* ws  = (float*)d_ws;
    float* out = (float*)d_out;

    prep_kernel<<<96, 256, 0, stream>>>(emb, tw, rank, ws);
    dist_kernel<<<NB / 2, NB, 0, stream>>>(emb, ws + ET_OFF, ws + D_OFF);
    loss_kernel<<<NB, 512, 0, stream>>>(
        ws + D_OFF, reinterpret_cast<const unsigned*>(ws + RP_OFF),
        ws + WF_OFF, ws + PART_OFF);
    reduce_kernel<<<1, 256, 0, stream>>>(ws + PART_OFF, out);
}

// Round 6
// 33.478 us; speedup vs baseline: 1.3420x; 1.0161x over previous
//
#include <hip/hip_runtime.h>

#define NB   384
#define ND   256
#define EPSF 1e-6f

// ws layout (floats):
#define WF_OFF   0                      // wf[4] = tw_t / count_t
#define PART_OFF 16                     // partial[384]
#define RP_OFF   512                    // rp[384] (u32 packed ranks)
#define ET_OFF   1024                   // ET[256][384] = emb^T - eps
#define D_OFF    (ET_OFF + ND * NB)     // D[384][384]

// ---------------------------------------------------------------------------
// K1: transpose emb -> ET[d][j] = e[j][d] - eps; block 0: per-task weights
// wf[t] = tw_t / count_t (analytic count from rank histogram); block 1: pack
// ranks rp[j] = r0|r1<<8|r2<<16|r3<<24.
// ---------------------------------------------------------------------------
__global__ __launch_bounds__(256) void prep_kernel(
    const float* __restrict__ emb,
    const float* __restrict__ tw,
    const int*   __restrict__ rank,
    float* __restrict__ ws)
{
    __shared__ float    t[32][33];
    __shared__ unsigned hist[20];

    const int tid = threadIdx.x;
    const int dt  = blockIdx.x & 7;
    const int jt  = blockIdx.x >> 3;
    const int c   = tid & 31;
    const int r8  = tid >> 5;

    #pragma unroll
    for (int p = 0; p < 4; ++p) {
        const int j = jt * 32 + r8 + p * 8;
        const int d = dt * 32 + c;
        t[r8 + p * 8][c] = emb[(size_t)j * ND + d];
    }
    __syncthreads();
    float* ET = ws + ET_OFF;
    #pragma unroll
    for (int p = 0; p < 4; ++p) {
        const int d = dt * 32 + r8 + p * 8;
        const int j = jt * 32 + c;
        ET[(size_t)d * NB + j] = t[c][r8 + p * 8] - EPSF;
    }

    if (blockIdx.x == 0) {
        if (tid < 20) hist[tid] = 0u;
        __syncthreads();
        for (int e = tid; e < NB * 4; e += 256)
            atomicAdd(&hist[(e & 3) * 5 + rank[e]], 1u);
        __syncthreads();
        if (tid < 4) {
            double cnt = 0.0;
            unsigned below = 0;
            #pragma unroll
            for (int v = 0; v < 5; ++v) {
                unsigned hv = hist[tid * 5 + v];
                unsigned above = (unsigned)NB - below - hv;
                cnt += (double)hv * (double)below * (double)above;
                below += hv;
            }
            ws[WF_OFF + tid] = (cnt > 0.0) ? (float)((double)tw[tid] / cnt) : 0.f;
        }
    }
    if (blockIdx.x == 1) {
        unsigned* rp = reinterpret_cast<unsigned*>(ws + RP_OFF);
        for (int j = tid; j < NB; j += 256) {
            const int4 r4 = *reinterpret_cast<const int4*>(rank + j * 4);
            rp[j] = (unsigned)r4.x | ((unsigned)r4.y << 8) |
                    ((unsigned)r4.z << 16) | ((unsigned)r4.w << 24);
        }
    }
}

// ---------------------------------------------------------------------------
// K2: D[i][j] = sqrt(sum_d (e_i[d] - (e_j[d]-eps))^2). 2 i-rows per block;
// ET reads lane-coalesced, e_i rows wave-uniform (scalar path).
// ---------------------------------------------------------------------------
__global__ __launch_bounds__(384) void dist_kernel(
    const float* __restrict__ emb,
    const float* __restrict__ et,
    float* __restrict__ D)
{
    const int j  = threadIdx.x;
    const int i0 = blockIdx.x * 2;
    const float* e0 = emb + (size_t)i0 * ND;
    const float* e1 = e0 + ND;

    float a0 = 0.f, a1 = 0.f;
    #pragma unroll 8
    for (int d = 0; d < ND; ++d) {
        const float ev = et[(size_t)d * NB + j];
        const float t0 = e0[d] - ev;
        const float t1 = e1[d] - ev;
        a0 = fmaf(t0, t0, a0);
        a1 = fmaf(t1, t1, a1);
    }
    D[(size_t)i0 * NB + j]       = sqrtf(a0);
    D[(size_t)(i0 + 1) * NB + j] = sqrtf(a1);
}

// ---------------------------------------------------------------------------
// K3: one block per row i. Bitonic-sort (d, rankpack) ascending by d (512 slots,
// +INF pads). Then per sorted position p (= both a j-role and a k-role):
//   j-role:  + thr_p * sum_t wf_t * #{q<P: r^t_q < r^t_p}      [r^t_p < r^t_i]
//   k-role:  - d_p  * sum_t wf_t * #{q>=Q: r^t_k < r^t_q < r^t_i}
// with P = #{q: d_q < thr_p}, Q = #{q: d_q+1 <= d_p}  (identical float
// predicate on both sides -> pair sets match exactly).
// Counts come from per-wave cumulative-rank ballot masks + wave prefix table.
// ---------------------------------------------------------------------------
__global__ __launch_bounds__(512) void loss_kernel(
    const float*    __restrict__ D,
    const unsigned* __restrict__ rp,
    const float*    __restrict__ wf,
    float* __restrict__ partial)
{
    __shared__ unsigned long long sh64[512];
    __shared__ float ks[512];
    __shared__ unsigned long long cm[8][16];   // [wave][t*4+w]: mask of r^t <= w
    __shared__ unsigned cumtab[9][16];         // exclusive wave-prefix popcounts
    __shared__ float red[8];

    const int p  = threadIdx.x;
    const int bi = blockIdx.x;

    unsigned long long kv;
    if (p < NB) {
        const unsigned kb = __float_as_uint(D[(size_t)bi * NB + p]); // d>0: bit order == value order
        kv = ((unsigned long long)kb << 32) | rp[p];
    } else {
        kv = 0x7F800000FFFFFFFFull;            // +INF key, rank bytes 0xFF (excluded)
    }

    // bitonic sort, value-in-register
    for (int size = 2; size <= 512; size <<= 1) {
        for (int stride = size >> 1; stride > 0; stride >>= 1) {
            sh64[p] = kv;
            __syncthreads();
            const unsigned long long other = sh64[p ^ stride];
            __syncthreads();
            const bool keepMin = ((p & stride) == 0) == ((p & size) == 0);
            const bool less = kv < other;
            kv = (less == keepMin) ? kv : other;
        }
    }

    const unsigned rsv = (unsigned)kv;                       // own sorted rank pack
    ks[p] = __uint_as_float((unsigned)(kv >> 32));           // own sorted distance
    const int wv = p >> 6;
    #pragma unroll
    for (int t = 0; t < 4; ++t) {
        const unsigned rt = (rsv >> (8 * t)) & 0xFFu;
        #pragma unroll
        for (int w = 0; w < 4; ++w) {
            const unsigned long long m = __ballot(rt <= (unsigned)w);
            if ((p & 63) == 0) cm[wv][t * 4 + w] = m;
        }
    }
    __syncthreads();
    if (p < 16) {
        unsigned c = 0;
        #pragma unroll
        for (int w2 = 0; w2 < 8; ++w2) {
            cumtab[w2][p] = c;
            c += (unsigned)__popcll(cm[w2][p]);
        }
        cumtab[8][p] = c;                                    // totals (pads excluded by rank filter)
    }
    __syncthreads();

    float contrib = 0.f;
    if (p < NB) {
        const float key = ks[p];
        const float thr = key + 1.0f;

        int P = 0;                                           // #{q: ks[q] < thr}
        #pragma unroll
        for (int s = 256; s > 0; s >>= 1) {
            const int cand = P + s;
            if (ks[cand - 1] < thr) P = cand;
        }
        int Q = 0;                                           // #{q: ks[q]+1 <= key}
        #pragma unroll
        for (int s = 256; s > 0; s >>= 1) {
            const int cand = Q + s;
            if (ks[cand - 1] + 1.0f <= key) Q = cand;
        }

        const int Pwv = P >> 6, Qwv = Q >> 6;
        const unsigned long long Pmask = (1ull << (P & 63)) - 1ull;
        const unsigned long long Qmask = (1ull << (Q & 63)) - 1ull;
        const unsigned rip = rp[bi];                         // row-i ranks (uniform)

        float jacc = 0.f, kacc = 0.f;
        #pragma unroll
        for (int t = 0; t < 4; ++t) {
            const int ri = (int)((rip >> (8 * t)) & 0xFFu);
            const int ro = (int)((rsv >> (8 * t)) & 0xFFu);  // own rank (j-role and k-role)
            const float wt = wf[t];
            if (ro > 0 && ro < ri) {                         // j-role
                const int w = t * 4 + (ro - 1);
                const unsigned N = cumtab[Pwv][w] +
                                   (unsigned)__popcll(cm[Pwv][w] & Pmask);
                jacc += wt * (float)N;
            }
            if (ro + 1 < ri) {                               // k-role: ranks in (ro, ri)
                const int wh = t * 4 + (ri - 1);
                const int wl = t * 4 + ro;
                const unsigned cQh = cumtab[Qwv][wh] +
                                     (unsigned)__popcll(cm[Qwv][wh] & Qmask);
                const unsigned cQl = cumtab[Qwv][wl] +
                                     (unsigned)__popcll(cm[Qwv][wl] & Qmask);
                const unsigned C = (cumtab[8][wh] - cQh) - (cumtab[8][wl] - cQl);
                kacc += wt * (float)C;
            }
        }
        contrib = jacc * thr - kacc * key;
    }

    #pragma unroll
    for (int off = 32; off > 0; off >>= 1)
        contrib += __shfl_down(contrib, off);
    if ((p & 63) == 0) red[p >> 6] = contrib;
    __syncthreads();
    if (p == 0) {
        float s = 0.f;
        #pragma unroll
        for (int q = 0; q < 8; ++q) s += red[q];
        partial[bi] = s;
    }
}

// ---------------------------------------------------------------------------
// K4: reduce 384 partials -> out[0]
// ---------------------------------------------------------------------------
__global__ __launch_bounds__(256) void reduce_kernel(
    const float* __restrict__ partial, float* __restrict__ out)
{
    __shared__ float r[4];
    const int tid = threadIdx.x;
    float t = 0.f;
    for (int p = tid; p < NB; p += 256) t += partial[p];
    #pragma unroll
    for (int off = 32; off > 0; off >>= 1)
        t += __shfl_down(t, off);
    if ((tid & 63) == 0) r[tid >> 6] = t;
    __syncthreads();
    if (tid == 0) out[0] = r[0] + r[1] + r[2] + r[3];
}

extern "C" void kernel_launch(void* const* d_in, const int* in_sizes, int n_in,
                              void* d_out, int out_size, void* d_ws, size_t ws_size,
                              hipStream_t stream)
{
    (void)in_sizes; (void)n_in; (void)out_size; (void)ws_size;
    const float* emb  = (const float*)d_in[0];
    const float* tw   = (const float*)d_in[1];
    const int*   rank = (const int*)d_in[2];
    float* ws  = (float*)d_ws;
    float* out = (float*)d_out;

    prep_kernel<<<96, 256, 0, stream>>>(emb, tw, rank, ws);
    dist_kernel<<<NB / 2, NB, 0, stream>>>(emb, ws + ET_OFF, ws + D_OFF);
    loss_kernel<<<NB, 512, 0, stream>>>(
        ws + D_OFF, reinterpret_cast<const unsigned*>(ws + RP_OFF),
        ws + WF_OFF, ws + PART_OFF);
    reduce_kernel<<<1, 256, 0, stream>>>(ws + PART_OFF, out);
}

// Round 7
// 25.427 us; speedup vs baseline: 1.7670x; 1.3167x over previous
//
#include <hip/hip_runtime.h>

#define NB   384
#define ND   256
#define EPSF 1e-6f

// ws layout (floats):
#define WF_OFF   0                      // wf[4] = tw_t / count_t
#define PART_OFF 16                     // partial[384]
#define RP_OFF   512                    // rp[384] packed ranks
#define ET_OFF   1024                   // ET[256][384] = emb^T - eps

// ---------------------------------------------------------------------------
// K1: transpose emb -> ET[d][j] = e[j][d] - eps; block 0: per-task weights
// wf[t] = tw_t / count_t (analytic); block 1: pack ranks.
// ---------------------------------------------------------------------------
__global__ __launch_bounds__(256) void prep_kernel(
    const float* __restrict__ emb,
    const float* __restrict__ tw,
    const int*   __restrict__ rank,
    float* __restrict__ ws)
{
    __shared__ float    t[32][33];
    __shared__ unsigned hist[20];

    const int tid = threadIdx.x;
    const int dt  = blockIdx.x & 7;
    const int jt  = blockIdx.x >> 3;
    const int c   = tid & 31;
    const int r8  = tid >> 5;

    #pragma unroll
    for (int p = 0; p < 4; ++p) {
        const int j = jt * 32 + r8 + p * 8;
        const int d = dt * 32 + c;
        t[r8 + p * 8][c] = emb[(size_t)j * ND + d];
    }
    __syncthreads();
    float* ET = ws + ET_OFF;
    #pragma unroll
    for (int p = 0; p < 4; ++p) {
        const int d = dt * 32 + r8 + p * 8;
        const int j = jt * 32 + c;
        ET[(size_t)d * NB + j] = t[c][r8 + p * 8] - EPSF;
    }

    if (blockIdx.x == 0) {
        if (tid < 20) hist[tid] = 0u;
        __syncthreads();
        for (int e = tid; e < NB * 4; e += 256)
            atomicAdd(&hist[(e & 3) * 5 + rank[e]], 1u);
        __syncthreads();
        if (tid < 4) {
            double cnt = 0.0;
            unsigned below = 0;
            #pragma unroll
            for (int v = 0; v < 5; ++v) {
                unsigned hv = hist[tid * 5 + v];
                unsigned above = (unsigned)NB - below - hv;
                cnt += (double)hv * (double)below * (double)above;
                below += hv;
            }
            ws[WF_OFF + tid] = (cnt > 0.0) ? (float)((double)tw[tid] / cnt) : 0.f;
        }
    }
    if (blockIdx.x == 1) {
        unsigned* rp = reinterpret_cast<unsigned*>(ws + RP_OFF);
        for (int j = tid; j < NB; j += 256) {
            const int4 r4 = *reinterpret_cast<const int4*>(rank + j * 4);
            rp[j] = (unsigned)r4.x | ((unsigned)r4.y << 8) |
                    ((unsigned)r4.z << 16) | ((unsigned)r4.w << 24);
        }
    }
}

// ---------------------------------------------------------------------------
// K2 (fused): one block per row i.
//  Phase 1: D-row from ET (batched-16 loads, e_i broadcast from LDS).
//  Phase 2: hybrid bitonic sort of 32-bit (quantized-key | idx); strides <64
//           in-register via shfl_xor (no barriers), >=64 via LDS (6 stages).
//  Phase 3: gather exact key/rankpack by idx, ballot cumulative-rank masks,
//           two fused binary searches, count-weighted contribution:
//    j-role: + thr_p * sum_t wf_t * #{q<P: r^t_q < r^t_p}       [r^t_p < r^t_i]
//    k-role: - d_p  * sum_t wf_t * #{q>=Q: r^t_p < r^t_q < r^t_i}
//  P = #{q: ks[q] < thr_p}, Q = #{q: ks[q]+1 <= d_p} (identical float
//  predicate both sides -> pair sets match).
// ---------------------------------------------------------------------------
__global__ __launch_bounds__(512, 2) void loss_kernel(
    const float*    __restrict__ emb,
    const float*    __restrict__ et,
    const unsigned* __restrict__ rp,
    const float*    __restrict__ wf,
    float* __restrict__ partial)
{
    __shared__ float    eil[ND];
    __shared__ float    dv[512];        // exact key by original index
    __shared__ unsigned rpl[512];       // rank pack by original index
    __shared__ unsigned s32[512];       // sort exchange buffer
    __shared__ float    ks[512];        // exact keys in sorted order
    __shared__ unsigned long long cm[8][16];
    __shared__ unsigned cumtab[9][16];
    __shared__ float    red[8];

    const int p  = threadIdx.x;
    const int bi = blockIdx.x;

    if (p < ND) eil[p] = emb[(size_t)bi * ND + p];
    if (p >= NB) { dv[p] = __int_as_float(0x7F800000); rpl[p] = 0xFFFFFFFFu; }
    __syncthreads();

    unsigned sk;
    if (p < NB) {
        float acc = 0.f;
        for (int d0 = 0; d0 < ND; d0 += 16) {
            float l[16];
            #pragma unroll
            for (int u = 0; u < 16; ++u)       // 16 independent loads in flight
                l[u] = et[(size_t)(d0 + u) * NB + p];
            #pragma unroll
            for (int u = 0; u < 16; ++u) {
                const float t = eil[d0 + u] - l[u];
                acc = fmaf(t, t, acc);
            }
        }
        const float key = sqrtf(acc);
        dv[p]  = key;
        rpl[p] = rp[p];
        sk = (__float_as_uint(key) & ~0x1FFu) | (unsigned)p;  // key|idx (d>0)
    } else {
        sk = 0xFFFFFFFFu;                // pads sort last
    }

    // hybrid bitonic sort (ascending). 45 stages: 39 shfl_xor + 6 LDS.
    #pragma unroll
    for (int size = 2; size <= 512; size <<= 1) {
        #pragma unroll
        for (int stride = size >> 1; stride > 0; stride >>= 1) {
            unsigned other;
            if (stride >= 64) {
                __syncthreads();         // WAR: protect s32 from prior stage
                s32[p] = sk;
                __syncthreads();
                other = s32[p ^ stride];
            } else {
                other = (unsigned)__shfl_xor((int)sk, stride, 64);
            }
            const bool keepMin = ((p & stride) == 0) == ((p & size) == 0);
            sk = ((sk < other) == keepMin) ? sk : other;
        }
    }

    // recover exact data for this sorted position
    const int idx = (int)(sk & 0x1FFu);
    __syncthreads();                     // s32 reads done; dv/rpl visible
    const float    key = dv[idx];        // permutation gather (~2-way, free)
    const unsigned rsv = rpl[idx];
    ks[p] = key;

    const int wv = p >> 6;
    #pragma unroll
    for (int t = 0; t < 4; ++t) {
        const unsigned rt = (rsv >> (8 * t)) & 0xFFu;
        #pragma unroll
        for (int w = 0; w < 4; ++w) {
            const unsigned long long m = __ballot(rt <= (unsigned)w);
            if ((p & 63) == 0) cm[wv][t * 4 + w] = m;
        }
    }
    __syncthreads();
    if (p < 16) {
        unsigned c = 0;
        #pragma unroll
        for (int w2 = 0; w2 < 8; ++w2) {
            cumtab[w2][p] = c;
            c += (unsigned)__popcll(cm[w2][p]);
        }
        cumtab[8][p] = c;
    }
    __syncthreads();

    float contrib = 0.f;
    if (p < NB) {
        const float thr = key + 1.0f;

        int P = 0, Q = 0;                // fused: two independent LDS chains
        #pragma unroll
        for (int s = 256; s > 0; s >>= 1) {
            if (ks[P + s - 1] < thr)         P += s;
            if (ks[Q + s - 1] + 1.0f <= key) Q += s;
        }

        const int Pwv = P >> 6, Qwv = Q >> 6;
        const unsigned long long Pmask = (1ull << (P & 63)) - 1ull;
        const unsigned long long Qmask = (1ull << (Q & 63)) - 1ull;
        const unsigned rip = rp[bi];

        float jacc = 0.f, kacc = 0.f;
        #pragma unroll
        for (int t = 0; t < 4; ++t) {
            const int ri = (int)((rip >> (8 * t)) & 0xFFu);
            const int ro = (int)((rsv >> (8 * t)) & 0xFFu);
            const float wt = wf[t];
            if (ro > 0 && ro < ri) {                       // j-role
                const int w = t * 4 + (ro - 1);
                const unsigned N = cumtab[Pwv][w] +
                                   (unsigned)__popcll(cm[Pwv][w] & Pmask);
                jacc += wt * (float)N;
            }
            if (ro + 1 < ri) {                             // k-role
                const int wh = t * 4 + (ri - 1);
                const int wl = t * 4 + ro;
                const unsigned cQh = cumtab[Qwv][wh] +
                                     (unsigned)__popcll(cm[Qwv][wh] & Qmask);
                const unsigned cQl = cumtab[Qwv][wl] +
                                     (unsigned)__popcll(cm[Qwv][wl] & Qmask);
                const unsigned C = (cumtab[8][wh] - cQh) - (cumtab[8][wl] - cQl);
                kacc += wt * (float)C;
            }
        }
        contrib = jacc * thr - kacc * key;
    }

    #pragma unroll
    for (int off = 32; off > 0; off >>= 1)
        contrib += __shfl_down(contrib, off);
    if ((p & 63) == 0) red[p >> 6] = contrib;
    __syncthreads();
    if (p == 0) {
        float s = 0.f;
        #pragma unroll
        for (int q = 0; q < 8; ++q) s += red[q];
        partial[bi] = s;
    }
}

// ---------------------------------------------------------------------------
// K3: reduce 384 partials -> out[0]
// ---------------------------------------------------------------------------
__global__ __launch_bounds__(256) void reduce_kernel(
    const float* __restrict__ partial, float* __restrict__ out)
{
    __shared__ float r[4];
    const int tid = threadIdx.x;
    float t = 0.f;
    for (int p = tid; p < NB; p += 256) t += partial[p];
    #pragma unroll
    for (int off = 32; off > 0; off >>= 1)
        t += __shfl_down(t, off);
    if ((tid & 63) == 0) r[tid >> 6] = t;
    __syncthreads();
    if (tid == 0) out[0] = r[0] + r[1] + r[2] + r[3];
}

extern "C" void kernel_launch(void* const* d_in, const int* in_sizes, int n_in,
                              void* d_out, int out_size, void* d_ws, size_t ws_size,
                              hipStream_t stream)
{
    (void)in_sizes; (void)n_in; (void)out_size; (void)ws_size;
    const float* emb  = (const float*)d_in[0];
    const float* tw   = (const float*)d_in[1];
    const int*   rank = (const int*)d_in[2];
    float* ws  = (float*)d_ws;
    float* out = (float*)d_out;

    prep_kernel<<<96, 256, 0, stream>>>(emb, tw, rank, ws);
    loss_kernel<<<NB, 512, 0, stream>>>(
        emb, ws + ET_OFF, reinterpret_cast<const unsigned*>(ws + RP_OFF),
        ws + WF_OFF, ws + PART_OFF);
    reduce_kernel<<<1, 256, 0, stream>>>(ws + PART_OFF, out);
}